// Round 19
// baseline (251.522 us; speedup 1.0000x reference)
//
#include <hip/hip_runtime.h>
#include <math.h>

namespace {

constexpr int kB  = 2;
constexpr int kL  = 8192;
constexpr int kD  = 768;
constexpr int HR  = 8240;  // hp16 row stride (f16): [32 zeros][8192 h][16 zero pad]
constexpr int UR  = 8200;  // ur row stride (f16): ur[8192 - t] = u[t]

typedef _Float16 f16;
typedef __attribute__((ext_vector_type(4))) _Float16 f16x4;
typedef __attribute__((ext_vector_type(8))) _Float16 f16x8;
typedef __attribute__((ext_vector_type(4))) float f32x4;

__device__ __forceinline__ void gload_lds16(const f16* g, f16* l) {
  __builtin_amdgcn_global_load_lds(
      (__attribute__((address_space(1))) void*)(g),
      (__attribute__((address_space(3))) void*)(l), 16, 0, 0);
}

__device__ __forceinline__ void cvt8(const float* s, f16* d, int i) {
  float4 a = *(const float4*)(s + i);
  float4 b = *(const float4*)(s + i + 4);
  f16x8 v;
  v[0] = (f16)a.x; v[1] = (f16)a.y; v[2] = (f16)a.z; v[3] = (f16)a.w;
  v[4] = (f16)b.x; v[5] = (f16)b.y; v[6] = (f16)b.z; v[7] = (f16)b.w;
  *(f16x8*)(d + i) = v;
}

// ---------------- K0: fused fp32 -> fp16 conversions (3 buffers) ----------------
__global__ __launch_bounds__(256) void cvt3(
    const float* __restrict__ s1, f16* __restrict__ d1, int n1,
    const float* __restrict__ s2, f16* __restrict__ d2, int n2,
    const float* __restrict__ s3, f16* __restrict__ d3, int n3) {
  int i = (blockIdx.x * 256 + threadIdx.x) * 8;
  if (i < n1) { cvt8(s1, d1, i); return; }
  i -= n1;
  if (i < n2) { cvt8(s2, d2, i); return; }
  i -= n2;
  if (i < n3) cvt8(s3, d3, i);
}

// ============ K1/K6: 256x256, BK=64, kk-major phases + vectorized epilogue ==
template <int MODE>
__global__ __launch_bounds__(512, 2) void hgemm256(
    const f16* __restrict__ A, const f16* __restrict__ W,
    f16* __restrict__ q16, f16* __restrict__ kv16,
    float* __restrict__ C, int N) {
  constexpr int K  = 768;
  constexpr int NT = K / 64;        // 12 K-tiles
  constexpr int BUFE = 256 * 64;
  __shared__ f16 As[2 * BUFE];
  __shared__ f16 Bs[2 * BUFE];
  const int tid  = threadIdx.x;
  const int wid  = tid >> 6;
  const int lane = tid & 63;
  const int nwg = gridDim.x * gridDim.y;
  const int lin = blockIdx.y * gridDim.x + blockIdx.x;
  const int wg  = (lin & 7) * (nwg >> 3) + (lin >> 3);
  const int bm = wg / gridDim.x;
  const int bn = wg % gridDim.x;
  const int wr = wid >> 2, wc = wid & 3;
  const int fr = lane & 15, fq = lane >> 4;
  const int srow = tid >> 3;
  const int scg  = ((tid & 7) ^ (srow & 7)) * 8;
  const int rsw  = fr & 7;
  const f16* Ab = A + (size_t)bm * 256 * K;
  const f16* Wb = W + (size_t)bn * 256 * K;
  const int dstoff = wid * 512;

  f32x4 acc[8][4];
#pragma unroll
  for (int m = 0; m < 8; ++m)
#pragma unroll
    for (int n = 0; n < 4; ++n)
#pragma unroll
      for (int j = 0; j < 4; ++j) acc[m][n][j] = 0.f;

  auto STG_A = [&](int buf, int t, int i0, int i1) {
    const int k0 = t * 64;
    gload_lds16(Ab + (size_t)(i0 * 64 + srow) * K + k0 + scg,
                As + buf * BUFE + i0 * 4096 + dstoff);
    gload_lds16(Ab + (size_t)(i1 * 64 + srow) * K + k0 + scg,
                As + buf * BUFE + i1 * 4096 + dstoff);
  };
  auto STG_B = [&](int buf, int t, int i0, int i1) {
    const int k0 = t * 64;
    gload_lds16(Wb + (size_t)(i0 * 64 + srow) * K + k0 + scg,
                Bs + buf * BUFE + i0 * 4096 + dstoff);
    gload_lds16(Wb + (size_t)(i1 * 64 + srow) * K + k0 + scg,
                Bs + buf * BUFE + i1 * 4096 + dstoff);
  };

  // prologue ledger: A02(0) B01(0) B23(0) A13(0) A02(1)
  STG_A(0, 0, 0, 2);
  STG_B(0, 0, 0, 1);
  STG_B(0, 0, 2, 3);
  STG_A(0, 0, 1, 3);
  STG_A(1, 1, 0, 2);

  for (int t = 0; t < NT; ++t) {
    const int p = t & 1;
    const f16* Ac = As + p * BUFE;
    const f16* Bc = Bs + p * BUFE;
    const bool hasN1 = (t + 1 < NT);
    const bool hasN2 = (t + 2 < NT);

    if (hasN1) asm volatile("s_waitcnt vmcnt(2)" ::: "memory");
    else       asm volatile("s_waitcnt vmcnt(0)" ::: "memory");
    __builtin_amdgcn_sched_barrier(0);
    __builtin_amdgcn_s_barrier();
    __builtin_amdgcn_sched_barrier(0);

    // ---- P1: kk=0, mh=0 ----
    {
      const int ch = (fq ^ rsw) << 3;
      f16x8 bf[4], af[4];
#pragma unroll
      for (int n = 0; n < 4; ++n)
        bf[n] = *(const f16x8*)&Bc[(wc * 64 + n * 16 + fr) * 64 + ch];
#pragma unroll
      for (int m = 0; m < 4; ++m)
        af[m] = *(const f16x8*)&Ac[(wr * 128 + m * 16 + fr) * 64 + ch];
      if (hasN1) STG_B(p ^ 1, t + 1, 0, 1);
      asm volatile("s_waitcnt lgkmcnt(0)" ::: "memory");
      __builtin_amdgcn_sched_barrier(0);
      __builtin_amdgcn_s_setprio(1);
#pragma unroll
      for (int m = 0; m < 4; ++m)
#pragma unroll
        for (int n = 0; n < 4; ++n)
          acc[m][n] = __builtin_amdgcn_mfma_f32_16x16x32_f16(af[m], bf[n], acc[m][n], 0, 0, 0);
      __builtin_amdgcn_s_setprio(0);
      // ---- P2: kk=0, mh=1 (bf reused) ----
      f16x8 ag[4];
#pragma unroll
      for (int m = 0; m < 4; ++m)
        ag[m] = *(const f16x8*)&Ac[(wr * 128 + 64 + m * 16 + fr) * 64 + ch];
      if (hasN1) STG_B(p ^ 1, t + 1, 2, 3);
      asm volatile("s_waitcnt lgkmcnt(0)" ::: "memory");
      __builtin_amdgcn_sched_barrier(0);
      __builtin_amdgcn_s_setprio(1);
#pragma unroll
      for (int m = 0; m < 4; ++m)
#pragma unroll
        for (int n = 0; n < 4; ++n)
          acc[4 + m][n] = __builtin_amdgcn_mfma_f32_16x16x32_f16(ag[m], bf[n], acc[4 + m][n], 0, 0, 0);
      __builtin_amdgcn_s_setprio(0);
    }

    __builtin_amdgcn_sched_barrier(0);
    __builtin_amdgcn_s_barrier();
    __builtin_amdgcn_sched_barrier(0);

    // ---- P3: kk=1, mh=0 ----
    {
      const int ch = ((4 + fq) ^ rsw) << 3;
      f16x8 bf[4], af[4];
#pragma unroll
      for (int n = 0; n < 4; ++n)
        bf[n] = *(const f16x8*)&Bc[(wc * 64 + n * 16 + fr) * 64 + ch];
#pragma unroll
      for (int m = 0; m < 4; ++m)
        af[m] = *(const f16x8*)&Ac[(wr * 128 + m * 16 + fr) * 64 + ch];
      if (hasN1) STG_A(p ^ 1, t + 1, 1, 3);
      asm volatile("s_waitcnt lgkmcnt(0)" ::: "memory");
      __builtin_amdgcn_sched_barrier(0);
      __builtin_amdgcn_s_setprio(1);
#pragma unroll
      for (int m = 0; m < 4; ++m)
#pragma unroll
        for (int n = 0; n < 4; ++n)
          acc[m][n] = __builtin_amdgcn_mfma_f32_16x16x32_f16(af[m], bf[n], acc[m][n], 0, 0, 0);
      __builtin_amdgcn_s_setprio(0);
      // ---- P4: kk=1, mh=1 ----
      f16x8 ag[4];
#pragma unroll
      for (int m = 0; m < 4; ++m)
        ag[m] = *(const f16x8*)&Ac[(wr * 128 + 64 + m * 16 + fr) * 64 + ch];
      if (hasN2) STG_A(p, t + 2, 0, 2);
      asm volatile("s_waitcnt lgkmcnt(0)" ::: "memory");
      __builtin_amdgcn_sched_barrier(0);
      __builtin_amdgcn_s_setprio(1);
#pragma unroll
      for (int m = 0; m < 4; ++m)
#pragma unroll
        for (int n = 0; n < 4; ++n)
          acc[4 + m][n] = __builtin_amdgcn_mfma_f32_16x16x32_f16(ag[m], bf[n], acc[4 + m][n], 0, 0, 0);
      __builtin_amdgcn_s_setprio(0);
    }
  }

  // ---- epilogue: LDS-transposed, vectorized coalesced stores ----
  __builtin_amdgcn_s_barrier();   // tile buffers now dead; safe to repurpose
  if constexpr (MODE == 0) {
    // per wave: 64-row x 64-col f16 slice, stride 72 (bank-rotating, 16B ok)
    f16* epi = ((wid < 4) ? As : Bs) + (wid & 3) * (64 * 72);
#pragma unroll
    for (int pp = 0; pp < 2; ++pp) {
#pragma unroll
      for (int m = 0; m < 4; ++m)
#pragma unroll
        for (int n = 0; n < 4; ++n)
#pragma unroll
          for (int j = 0; j < 4; ++j)
            epi[(m * 16 + fq * 4 + j) * 72 + n * 16 + fr] = (f16)acc[pp * 4 + m][n][j];
#pragma unroll
      for (int i = 0; i < 8; ++i) {
        const int item = i * 64 + lane;       // 64 rows x 8 chunks
        const int row = item >> 3, ck = item & 7;
        f16x8 v = *(const f16x8*)&epi[row * 72 + ck * 8];
        const int grow = bm * 256 + wr * 128 + pp * 64 + row;
        const int gcol = bn * 256 + wc * 64 + ck * 8;
        f16* dst;
        int ldc, col;
        if (gcol < 768) { dst = q16; ldc = 768; col = gcol; }
        else            { dst = kv16; ldc = 1536; col = gcol - 768; }
        *(f16x8*)&dst[(size_t)grow * ldc + col] = v;
      }
    }
  } else {
    // per wave: 64-row x 32-col f32 slice, stride 44 (16B-aligned rows)
    float* epi = (float*)(((wid < 4) ? As : Bs)) + (wid & 3) * (64 * 44);
#pragma unroll
    for (int pp = 0; pp < 2; ++pp)
#pragma unroll
      for (int h = 0; h < 2; ++h) {
#pragma unroll
        for (int m = 0; m < 4; ++m)
#pragma unroll
          for (int n = 0; n < 2; ++n)
#pragma unroll
            for (int j = 0; j < 4; ++j)
              epi[(m * 16 + fq * 4 + j) * 44 + n * 16 + fr] = acc[pp * 4 + m][h * 2 + n][j];
#pragma unroll
        for (int i = 0; i < 8; ++i) {
          const int item = i * 64 + lane;     // 64 rows x 8 chunks(4 f32)
          const int row = item >> 3, ck = item & 7;
          f32x4 v = *(const f32x4*)&epi[row * 44 + ck * 4];
          const int grow = bm * 256 + wr * 128 + pp * 64 + row;
          const int gcol = bn * 256 + wc * 64 + h * 32 + ck * 4;
          *(f32x4*)&C[(size_t)grow * N + gcol] = v;
        }
      }
  }
}

// ---------------- K2: dwconv(k=3) + product, vectorized, transpose+reverse ----------------
__global__ __launch_bounds__(256) void dwconv_mul(
    const f16* __restrict__ kv,
    const float* __restrict__ sck_w, const float* __restrict__ sck_b,
    const float* __restrict__ scv_w, const float* __restrict__ scv_b,
    f16* __restrict__ ur) {
  __shared__ float ks[66][72];
  __shared__ float vs[66][72];
  const int b  = blockIdx.z;
  const int d0 = blockIdx.y * 64;
  const int t0 = blockIdx.x * 64;
  const int i  = threadIdx.x;
  const f16* base = kv + (size_t)b * kL * (2 * kD);
  for (int r = i >> 3; r < 66; r += 32) {
    const int c = (i & 7) * 8;
    const int t = t0 - 1 + r;
    float4 ka = {0,0,0,0}, kb4 = {0,0,0,0}, va = {0,0,0,0}, vb = {0,0,0,0};
    if (t >= 0 && t < kL) {
      f16x8 kk = *(const f16x8*)&base[(size_t)t * (2 * kD) + d0 + c];
      f16x8 vv = *(const f16x8*)&base[(size_t)t * (2 * kD) + kD + d0 + c];
      ka = make_float4((float)kk[0], (float)kk[1], (float)kk[2], (float)kk[3]);
      kb4 = make_float4((float)kk[4], (float)kk[5], (float)kk[6], (float)kk[7]);
      va = make_float4((float)vv[0], (float)vv[1], (float)vv[2], (float)vv[3]);
      vb = make_float4((float)vv[4], (float)vv[5], (float)vv[6], (float)vv[7]);
    }
    *(float4*)&ks[r][c] = ka; *(float4*)&ks[r][c + 4] = kb4;
    *(float4*)&vs[r][c] = va; *(float4*)&vs[r][c + 4] = vb;
  }
  __syncthreads();
  const int dd = i & 63;
  const int d  = d0 + dd;
  const float kw0 = sck_w[d * 3 + 0], kw1 = sck_w[d * 3 + 1], kw2 = sck_w[d * 3 + 2];
  const float vw0 = scv_w[d * 3 + 0], vw1 = scv_w[d * 3 + 1], vw2 = scv_w[d * 3 + 2];
  const float kbi = sck_b[d], vbi = scv_b[d];
  f16* urow = ur + ((size_t)b * kD + d) * UR;
#pragma unroll
  for (int rep = 0; rep < 2; ++rep) {
    const int to = (i >> 6) + 4 * rep;
    const int R  = to * 8;
    float k0 = ks[R][dd],     k1 = ks[R + 1][dd];
    float v0 = vs[R][dd],     v1 = vs[R + 1][dd];
    f16x8 outv;
#pragma unroll
    for (int e = 0; e < 8; ++e) {
      float k2 = ks[R + 2 + e][dd];
      float v2 = vs[R + 2 + e][dd];
      float kc = kw0 * k0 + kw1 * k1 + kw2 * k2 + kbi;
      float vc = vw0 * v0 + vw1 * v1 + vw2 * v2 + vbi;
      outv[7 - e] = (f16)(kc * vc);
      k0 = k1; k1 = k2; v0 = v1; v1 = v2;
    }
    *(f16x8*)&urow[kL - t0 - to * 8 - 8] = outv;
  }
  if (t0 == 0 && i < 64) {
    float kc = kw1 * ks[0][dd] + kw2 * ks[1][dd] + kbi;
    float vc = vw1 * vs[0][dd] + vw2 * vs[1][dd] + vbi;
    urow[kL] = (f16)(kc * vc);
  }
}

// ---------------- K3: hyena filter (t-parallel) -> hp16[d][32 + t]; pads zeroed ----------------
__global__ __launch_bounds__(256) void hyena_filter(
    const float* __restrict__ w1, const float* __restrict__ b1,
    const float* __restrict__ w2, const float* __restrict__ b2,
    const float* __restrict__ w3, const float* __restrict__ b3,
    const float* __restrict__ log_decay, f16* __restrict__ hp16) {
  __shared__ float w1s[64 * 65];
  __shared__ float w2s[64 * 65];
  __shared__ float pe[32][65];
  __shared__ float h1s[32][65];
  __shared__ float h2s[32][64];
  const int tid = threadIdx.x;
  if (blockIdx.x == 0) {
    for (int d = tid; d < kD; d += 256) {
      f16* row = hp16 + (size_t)d * HR;
      *(f16x8*)&row[0]  = (f16x8){}; *(f16x8*)&row[8]  = (f16x8){};
      *(f16x8*)&row[16] = (f16x8){}; *(f16x8*)&row[24] = (f16x8){};
      *(f16x8*)&row[8224] = (f16x8){}; *(f16x8*)&row[8232] = (f16x8){};
    }
  }
  for (int i = tid; i < 64 * 64; i += 256) {
    w1s[(i >> 6) * 65 + (i & 63)] = w1[i];
    w2s[(i >> 6) * 65 + (i & 63)] = w2[i];
  }
  const int tbase = blockIdx.x * 32;
  const int tt = tid >> 3;
  const int oc = (tid & 7) * 8;
  const float TWO_PI = 6.28318530717958647692f;
  {
    float tn = (float)(tbase + tt) / 8191.0f;
#pragma unroll
    for (int e = 0; e < 8; ++e) {
      int j = oc + e;
      float f = TWO_PI * (float)((j & 31) + 1);
      pe[tt][j] = (j < 32) ? sinf(tn * f) : cosf(tn * f);
    }
  }
  __syncthreads();
  {
    float s[8];
#pragma unroll
    for (int e = 0; e < 8; ++e) s[e] = b1[oc + e];
    for (int j = 0; j < 64; ++j) {
      float p = pe[tt][j];
#pragma unroll
      for (int e = 0; e < 8; ++e) s[e] += p * w1s[(oc + e) * 65 + j];
    }
#pragma unroll
    for (int e = 0; e < 8; ++e) h1s[tt][oc + e] = s[e] / (1.0f + expf(-s[e]));
  }
  __syncthreads();
  {
    float s[8];
#pragma unroll
    for (int e = 0; e < 8; ++e) s[e] = b2[oc + e];
    for (int j = 0; j < 64; ++j) {
      float p = h1s[tt][j];
#pragma unroll
      for (int e = 0; e < 8; ++e) s[e] += p * w2s[(oc + e) * 65 + j];
    }
#pragma unroll
    for (int e = 0; e < 8; ++e) h2s[tt][oc + e] = s[e] / (1.0f + expf(-s[e]));
  }
  __syncthreads();
  for (int d = tid; d < kD; d += 256) {
    float a = fabsf(log_decay[d]);
    float bb = b3[d];
    float acc[32];
#pragma unroll
    for (int t2 = 0; t2 < 32; ++t2) acc[t2] = bb;
    for (int j = 0; j < 64; ++j) {
      float w = w3[d * 64 + j];
#pragma unroll
      for (int t2 = 0; t2 < 32; ++t2) acc[t2] += h2s[t2][j] * w;
    }
    for (int t2 = 0; t2 < 32; ++t2) {
      int t = tbase + t2;
      hp16[(size_t)d * HR + 32 + t] = (f16)(acc[t2] * expf(-a * (float)t));
    }
  }
}

// ---------------- truncation length ----------------
__device__ __forceinline__ int trunc_len(float a) {
  int Td = (a * (float)kL <= 16.0f) ? kL : ((int)(16.0f / a) + 1);
  Td = (Td + 7) & ~7;
  return min(Td, kL);
}

// ---------------- K4: long conv via MFMA Toeplitz, 4-wave s-split + prefetch ----------------
__device__ __forceinline__ void bmask(f16x8& v, int X) {
  if (X < 0 || X > kL) { v = (f16x8){}; return; }
  uint32_t* u = (uint32_t*)&v;
  if (X == 0)  { u[0] &= 0xFFFFu; u[1] = 0; u[2] = 0; u[3] = 0; }
  else if (X == kL) { u[0] &= 0xFFFF0000u; }
}
__global__ __launch_bounds__(256) void long_conv_mfma(
    const f16* __restrict__ ur, const f16* __restrict__ hp,
    const float* __restrict__ log_decay, f16* __restrict__ y16) {
  __shared__ float red[3][8][72];
  const int wid  = threadIdx.x >> 6;   // 0..3
  const int lane = threadIdx.x & 63;
  const int gb = blockIdx.x;           // 0..24575
  const int d  = gb >> 5;
  const int tc = gb & 31;
  const int T0 = tc << 8;
  const int fr = lane & 15, fq = lane >> 4;
  const float a = fabsf(log_decay[d]);
  const int S = min(trunc_len(a), T0 + 256);
  const int nck = (((S + 31) & ~31) >> 5) + 1;
  const f16* hrow = hp + (size_t)d * HR;
  const f16* u0 = ur + (size_t)d * UR;
  const f16* u1 = ur + (size_t)(kD + d) * UR;
  const int abase = 8 * fq + fr;
  const int xbase = T0 + 16 * fr - 8 * fq + 32;
  f32x4 acc0 = {0.f, 0.f, 0.f, 0.f};
  f32x4 acc1 = {0.f, 0.f, 0.f, 0.f};

  int c = wid;
  if (c < nck) {
    int s0 = c << 5;
    f16x8 af;
    {
      const f16* hb = hrow + s0 + abase;
#pragma unroll
      for (int e = 0; e < 8; ++e) af[e] = hb[e];
    }
    int X = xbase - s0;
    f16x8 b0 = *(const f16x8*)(u0 + (kL - X));
    f16x8 b1 = *(const f16x8*)(u1 + (kL - X));
    for (;;) {
      const int cn = c + 4;
      const bool more = cn < nck;
      f16x8 naf, nb0, nb1;
      int nX = 0;
      if (more) {
        const int s0n = cn << 5;
        const f16* hb = hrow + s0n + abase;
#pragma unroll
        for (int e = 0; e < 8; ++e) naf[e] = hb[e];
        nX = xbase - s0n;
        nb0 = *(const f16x8*)(u0 + (kL - nX));
        nb1 = *(const f16x8*)(u1 + (kL - nX));
      }
      bmask(b0, X);
      bmask(b1, X);
      acc0 = __builtin_amdgcn_mfma_f32_16x16x32_f16(af, b0, acc0, 0, 0, 0);
      acc1 = __builtin_amdgcn_mfma_f32_16x16x32_f16(af, b1, acc1, 0, 0, 0);
      if (!more) break;
      af = naf; b0 = nb0; b1 = nb1; X = nX; c = cn;
    }
  }

  if (wid != 0) {
#pragma unroll
    for (int j = 0; j < 4; ++j) {
      red[wid - 1][j][lane]     = acc0[j];
      red[wid - 1][4 + j][lane] = acc1[j];
    }
  }
  __syncthreads();
  if (wid == 0) {
#pragma unroll
    for (int w = 0; w < 3; ++w)
#pragma unroll
      for (int j = 0; j < 4; ++j) {
        acc0[j] += red[w][j][lane];
        acc1[j] += red[w][4 + j][lane];
      }
    const size_t off = (size_t)T0 + 16 * fr + 4 * fq;
    f16x4 o0, o1;
#pragma unroll
    for (int j = 0; j < 4; ++j) { o0[j] = (f16)acc0[j]; o1[j] = (f16)acc1[j]; }
    *(f16x4*)&y16[(size_t)d * kL + off] = o0;
    *(f16x4*)&y16[(size_t)(kD + d) * kL + off] = o1;
  }
}

// ---------------- K5: gate + transpose (vectorized) ----------------
__global__ __launch_bounds__(256) void gate_transpose(
    const f16* __restrict__ q, const f16* __restrict__ y16,
    f16* __restrict__ g) {
  __shared__ f16 ys[64][72];
  const int b  = blockIdx.z;
  const int t0 = blockIdx.x * 64;
  const int d0 = blockIdx.y * 64;
  const int i  = threadIdx.x;
#pragma unroll
  for (int rep = 0; rep < 2; ++rep) {
    const int dd = (i >> 3) + rep * 32;
    const int tc = i & 7;
    f16x8 v = *(const f16x8*)&y16[((size_t)b * kD + d0 + dd) * kL + t0 + tc * 8];
    *(f16x8*)&ys[dd][tc * 8] = v;
  }
  __syncthreads();
  const f16* qb = q + (size_t)b * kL * kD;
  f16* gb = g + (size_t)b * kL * kD;
#pragma unroll
  for (int rep = 0; rep < 2; ++rep) {
    const int tt = (i >> 3) + rep * 32;
    const int dc = i & 7;
    const size_t row = (size_t)(t0 + tt) * kD + d0 + dc * 8;
    f16x8 qv = *(const f16x8*)&qb[row];
    f16x8 ov;
#pragma unroll
    for (int e = 0; e < 8; ++e) {
      float qf = (float)qv[e];
      float sq = qf / (1.0f + expf(-qf));
      ov[e] = (f16)(sq * (float)ys[dc * 8 + e][tt]);
    }
    *(f16x8*)&gb[row] = ov;
  }
}

}  // namespace

extern "C" void kernel_launch(void* const* d_in, const int* in_sizes, int n_in,
                              void* d_out, int out_size, void* d_ws, size_t ws_size,
                              hipStream_t stream) {
  const float* x          = (const float*)d_in[0];
  const float* in_proj_w  = (const float*)d_in[1];
  const float* sck_w      = (const float*)d_in[2];
  const float* sck_b      = (const float*)d_in[3];
  const float* scv_w      = (const float*)d_in[4];
  const float* scv_b      = (const float*)d_in[5];
  const float* mlp_w1     = (const float*)d_in[6];
  const float* mlp_b1     = (const float*)d_in[7];
  const float* mlp_w2     = (const float*)d_in[8];
  const float* mlp_b2     = (const float*)d_in[9];
  const float* mlp_w3     = (const float*)d_in[10];
  const float* mlp_b3     = (const float*)d_in[11];
  const float* log_decay  = (const float*)d_in[12];
  const float* out_proj_w = (const float*)d_in[13];
  float* out = (float*)d_out;

  // workspace layout (bytes), ~143 MB total
  char* base = (char*)d_ws;
  const size_t S1  = 25165824;                      // q16  [B][L][D] fp16
  const size_t S2  = 50331648;                      // kv16 -> later y16 [B][D][L] f16
  const size_t Sur = (size_t)kB * kD * UR * 2;      // ur   reversed u
  const size_t S4  = 25165824;                      // x16 -> later g16
  const size_t Shp = (size_t)kD * HR * 2;           // hp16 padded filter
  f16*   q16   = (f16*)base;
  f16*   kv16  = (f16*)(base + S1);
  f16*   y16   = (f16*)(base + S1);                 // overlays kv16 after K2
  f16*   ur    = (f16*)(base + S1 + S2);
  f16*   x16   = (f16*)(base + S1 + S2 + Sur);
  f16*   g16   = x16;
  f16*   hp16  = (f16*)(base + S1 + S2 + Sur + S4);
  f16*   w16in = (f16*)(base + S1 + S2 + Sur + S4 + Shp);
  f16*   w16out= w16in + (size_t)3 * kD * kD;

  // K0: fused fp32 -> fp16 conversions (x, in_proj_w, out_proj_w)
  {
    const int n1 = kB * kL * kD;
    const int n2 = 3 * kD * kD;
    const int n3 = kD * kD;
    const int total8 = (n1 + n2 + n3) / 8;
    cvt3<<<(total8 + 255) / 256, 256, 0, stream>>>(
        x, x16, n1, in_proj_w, w16in, n2, out_proj_w, w16out, n3);
  }

  // K1: {q16, kv16} = x16 @ w16in^T  (M=16384, N=2304, K=768)
  hgemm256<0><<<dim3(9, 64), 512, 0, stream>>>(
      x16, w16in, q16, kv16, nullptr, 0);

  // K2: ur[b,d,kL-t] = conv_k * conv_v  (vectorized 64x64 tiles)
  dwconv_mul<<<dim3(kL / 64, kD / 64, kB), 256, 0, stream>>>(
      kv16, sck_w, sck_b, scv_w, scv_b, ur);

  // K3: filter hp16[d][32+t]  (t-parallel; zeroes its own pads)
  hyena_filter<<<dim3(kL / 32), 256, 0, stream>>>(
      mlp_w1, mlp_b1, mlp_w2, mlp_b2, mlp_w3, mlp_b3, log_decay, hp16);

  // K4: y16 = causal conv via MFMA Toeplitz; block per (d, t-tile), 4-wave s-split
  long_conv_mfma<<<kD * 32, 256, 0, stream>>>(ur, hp16, log_decay, y16);

  // K5: g16[b,t,d] = silu(q16) * y16  (vectorized 64x64 tiles)
  gate_transpose<<<dim3(kL / 64, kD / 64, kB), 256, 0, stream>>>(q16, y16, g16);

  // K6: out = g16 @ w16out^T  (M=16384, N=768, K=768)
  hgemm256<1><<<dim3(3, 64), 512, 0, stream>>>(
      g16, w16out, nullptr, nullptr, out, kD);
}

// Round 20
// 236.868 us; speedup vs baseline: 1.0619x; 1.0619x over previous
//
#include <hip/hip_runtime.h>
#include <math.h>

namespace {

constexpr int kB  = 2;
constexpr int kL  = 8192;
constexpr int kD  = 768;
constexpr int HR  = 8240;  // hp16 row stride (f16): [32 zeros][8192 h][16 zero pad]
constexpr int UR  = 8200;  // ur row stride (f16): ur[8192 - t] = u[t]

typedef _Float16 f16;
typedef __attribute__((ext_vector_type(4))) _Float16 f16x4;
typedef __attribute__((ext_vector_type(8))) _Float16 f16x8;
typedef __attribute__((ext_vector_type(4))) float f32x4;

__device__ __forceinline__ void gload_lds16(const f16* g, f16* l) {
  __builtin_amdgcn_global_load_lds(
      (__attribute__((address_space(1))) void*)(g),
      (__attribute__((address_space(3))) void*)(l), 16, 0, 0);
}

__device__ __forceinline__ void cvt8(const float* s, f16* d, int i) {
  float4 a = *(const float4*)(s + i);
  float4 b = *(const float4*)(s + i + 4);
  f16x8 v;
  v[0] = (f16)a.x; v[1] = (f16)a.y; v[2] = (f16)a.z; v[3] = (f16)a.w;
  v[4] = (f16)b.x; v[5] = (f16)b.y; v[6] = (f16)b.z; v[7] = (f16)b.w;
  *(f16x8*)(d + i) = v;
}

// ---------------- K0: fused fp32 -> fp16 conversions (3 buffers) ----------------
__global__ __launch_bounds__(256) void cvt3(
    const float* __restrict__ s1, f16* __restrict__ d1, int n1,
    const float* __restrict__ s2, f16* __restrict__ d2, int n2,
    const float* __restrict__ s3, f16* __restrict__ d3, int n3) {
  int i = (blockIdx.x * 256 + threadIdx.x) * 8;
  if (i < n1) { cvt8(s1, d1, i); return; }
  i -= n1;
  if (i < n2) { cvt8(s2, d2, i); return; }
  i -= n2;
  if (i < n3) cvt8(s3, d3, i);
}

// ============ K1/K6: 256x192 tile, BK=64, mh-major phases, counted vmcnt ====
// Grid fits CU count exactly (K1: 768 blks = 3 rounds; K6: 256 = 1 round).
// Waves 2Mx4N, wave tile 128x48, acc[8][3]; bf(kk0)/bf(kk1) kept in regs
// across the mid barrier (22 ds_read_b128 / K-tile).
// Stage slots: P1:B01(t+1) P2:B2+A1(t+1) P3:A3(t+1) P4:A02(t+2, live buf —
// safe: A02 readers are P1/P2, drained before mid barrier).
// Head wait vmcnt(2) steady / vmcnt(0) tail; ledger verified.
template <int MODE>
__global__ __launch_bounds__(512, 2) void hgemm256(
    const f16* __restrict__ A, const f16* __restrict__ W,
    f16* __restrict__ q16, f16* __restrict__ kv16,
    float* __restrict__ C, int N) {
  constexpr int K  = 768;
  constexpr int NT = K / 64;          // 12 K-tiles
  constexpr int BUFA = 256 * 64;      // f16 elems per A tile buffer
  constexpr int BUFB = 192 * 64;      // f16 elems per B tile buffer
  __shared__ f16 As[2 * BUFA];        // 64 KB
  __shared__ f16 Bs[2 * BUFB];        // 48 KB
  const int tid  = threadIdx.x;
  const int wid  = tid >> 6;
  const int lane = tid & 63;
  const int nwg = gridDim.x * gridDim.y;
  const int lin = blockIdx.y * gridDim.x + blockIdx.x;
  const int wg  = (lin & 7) * (nwg >> 3) + (lin >> 3);
  const int bm = wg / gridDim.x;
  const int bn = wg % gridDim.x;
  const int wr = wid >> 2, wc = wid & 3;
  const int fr = lane & 15, fq = lane >> 4;
  const int srow = tid >> 3;
  const int scg  = ((tid & 7) ^ (srow & 7)) * 8;
  const int rsw  = fr & 7;
  const f16* Ab = A + (size_t)bm * 256 * K;
  const f16* Wb = W + (size_t)bn * 192 * K;
  const int dstoff = wid * 512;

  f32x4 acc[8][3];
#pragma unroll
  for (int m = 0; m < 8; ++m)
#pragma unroll
    for (int n = 0; n < 3; ++n)
#pragma unroll
      for (int j = 0; j < 4; ++j) acc[m][n][j] = 0.f;

  auto STG_A1 = [&](int buf, int t, int i) {
    gload_lds16(Ab + (size_t)(i * 64 + srow) * K + t * 64 + scg,
                As + buf * BUFA + i * 4096 + dstoff);
  };
  auto STG_B1 = [&](int buf, int t, int i) {
    gload_lds16(Wb + (size_t)(i * 64 + srow) * K + t * 64 + scg,
                Bs + buf * BUFB + i * 4096 + dstoff);
  };

  // prologue ledger: A02(0) B01(0) B2(0)A1(0) A3(0) A02(1)
  STG_A1(0, 0, 0); STG_A1(0, 0, 2);
  STG_B1(0, 0, 0); STG_B1(0, 0, 1);
  STG_B1(0, 0, 2); STG_A1(0, 0, 1);
  STG_A1(0, 0, 3);
  STG_A1(1, 1, 0); STG_A1(1, 1, 2);

  for (int t = 0; t < NT; ++t) {
    const int p = t & 1;
    const f16* Ac = As + p * BUFA;
    const f16* Bc = Bs + p * BUFB;
    const bool hasN1 = (t + 1 < NT);
    const bool hasN2 = (t + 2 < NT);

    if (hasN1) asm volatile("s_waitcnt vmcnt(2)" ::: "memory");
    else       asm volatile("s_waitcnt vmcnt(0)" ::: "memory");
    __builtin_amdgcn_sched_barrier(0);
    __builtin_amdgcn_s_barrier();
    __builtin_amdgcn_sched_barrier(0);

    const int ch0 = (fq ^ rsw) << 3;
    const int ch1 = ((4 + fq) ^ rsw) << 3;
    f16x8 bf0[3], bf1[3], af[4];

    // ---- P1: mh0, kk0 ----
#pragma unroll
    for (int n = 0; n < 3; ++n)
      bf0[n] = *(const f16x8*)&Bc[(wc * 48 + n * 16 + fr) * 64 + ch0];
#pragma unroll
    for (int m = 0; m < 4; ++m)
      af[m] = *(const f16x8*)&Ac[(wr * 128 + m * 16 + fr) * 64 + ch0];
    if (hasN1) { STG_B1(p ^ 1, t + 1, 0); STG_B1(p ^ 1, t + 1, 1); }
    asm volatile("s_waitcnt lgkmcnt(0)" ::: "memory");
    __builtin_amdgcn_sched_barrier(0);
    __builtin_amdgcn_s_setprio(1);
#pragma unroll
    for (int m = 0; m < 4; ++m)
#pragma unroll
      for (int n = 0; n < 3; ++n)
        acc[m][n] = __builtin_amdgcn_mfma_f32_16x16x32_f16(af[m], bf0[n], acc[m][n], 0, 0, 0);
    __builtin_amdgcn_s_setprio(0);

    // ---- P2: mh0, kk1 ----
#pragma unroll
    for (int n = 0; n < 3; ++n)
      bf1[n] = *(const f16x8*)&Bc[(wc * 48 + n * 16 + fr) * 64 + ch1];
#pragma unroll
    for (int m = 0; m < 4; ++m)
      af[m] = *(const f16x8*)&Ac[(wr * 128 + m * 16 + fr) * 64 + ch1];
    if (hasN1) { STG_B1(p ^ 1, t + 1, 2); STG_A1(p ^ 1, t + 1, 1); }
    asm volatile("s_waitcnt lgkmcnt(0)" ::: "memory");
    __builtin_amdgcn_sched_barrier(0);
    __builtin_amdgcn_s_setprio(1);
#pragma unroll
    for (int m = 0; m < 4; ++m)
#pragma unroll
      for (int n = 0; n < 3; ++n)
        acc[m][n] = __builtin_amdgcn_mfma_f32_16x16x32_f16(af[m], bf1[n], acc[m][n], 0, 0, 0);
    __builtin_amdgcn_s_setprio(0);

    // mid barrier: all A02(p) reads complete block-wide
    __builtin_amdgcn_sched_barrier(0);
    __builtin_amdgcn_s_barrier();
    __builtin_amdgcn_sched_barrier(0);

    // ---- P3: mh1, kk0 (bf0 reused) ----
#pragma unroll
    for (int m = 0; m < 4; ++m)
      af[m] = *(const f16x8*)&Ac[(wr * 128 + 64 + m * 16 + fr) * 64 + ch0];
    if (hasN1) STG_A1(p ^ 1, t + 1, 3);
    asm volatile("s_waitcnt lgkmcnt(0)" ::: "memory");
    __builtin_amdgcn_sched_barrier(0);
    __builtin_amdgcn_s_setprio(1);
#pragma unroll
    for (int m = 0; m < 4; ++m)
#pragma unroll
      for (int n = 0; n < 3; ++n)
        acc[4 + m][n] = __builtin_amdgcn_mfma_f32_16x16x32_f16(af[m], bf0[n], acc[4 + m][n], 0, 0, 0);
    __builtin_amdgcn_s_setprio(0);

    // ---- P4: mh1, kk1 (bf1 reused) ----
#pragma unroll
    for (int m = 0; m < 4; ++m)
      af[m] = *(const f16x8*)&Ac[(wr * 128 + 64 + m * 16 + fr) * 64 + ch1];
    if (hasN2) { STG_A1(p, t + 2, 0); STG_A1(p, t + 2, 2); }
    asm volatile("s_waitcnt lgkmcnt(0)" ::: "memory");
    __builtin_amdgcn_sched_barrier(0);
    __builtin_amdgcn_s_setprio(1);
#pragma unroll
    for (int m = 0; m < 4; ++m)
#pragma unroll
      for (int n = 0; n < 3; ++n)
        acc[4 + m][n] = __builtin_amdgcn_mfma_f32_16x16x32_f16(af[m], bf1[n], acc[4 + m][n], 0, 0, 0);
    __builtin_amdgcn_s_setprio(0);
  }

  // ---- epilogue: LDS-transposed, vectorized coalesced stores ----
  __builtin_amdgcn_s_barrier();   // tile buffers dead; repurpose
  if constexpr (MODE == 0) {
    // per wave: 64 rows x 48 cols f16, stride 56
    f16* epi = As + wid * (64 * 56);
    const int myrow = lane / 6, myck = lane % 6;   // for readback mapping
#pragma unroll
    for (int pp = 0; pp < 2; ++pp) {
#pragma unroll
      for (int m = 0; m < 4; ++m)
#pragma unroll
        for (int n = 0; n < 3; ++n)
#pragma unroll
          for (int j = 0; j < 4; ++j)
            epi[(m * 16 + fq * 4 + j) * 56 + n * 16 + fr] = (f16)acc[pp * 4 + m][n][j];
#pragma unroll
      for (int i = 0; i < 6; ++i) {
        const int item = i * 64 + lane;           // 64 rows x 6 chunks
        const int row = item / 6, ck = item % 6;
        f16x8 v = *(const f16x8*)&epi[row * 56 + ck * 8];
        const int grow = bm * 256 + wr * 128 + pp * 64 + row;
        const int gcol = bn * 192 + wc * 48 + ck * 8;
        f16* dst;
        int ldc, col;
        if (gcol < 768) { dst = q16; ldc = 768; col = gcol; }
        else            { dst = kv16; ldc = 1536; col = gcol - 768; }
        *(f16x8*)&dst[(size_t)grow * ldc + col] = v;
      }
    }
    (void)myrow; (void)myck;
  } else {
    // per wave: 64 rows x 48 cols f32, stride 48; waves 0-3 in As, 4-7 in Bs
    float* epi = (wid < 4) ? ((float*)As + wid * (64 * 48))
                           : ((float*)Bs + (wid - 4) * (64 * 48));
#pragma unroll
    for (int pp = 0; pp < 2; ++pp) {
#pragma unroll
      for (int m = 0; m < 4; ++m)
#pragma unroll
        for (int n = 0; n < 3; ++n)
#pragma unroll
          for (int j = 0; j < 4; ++j)
            epi[(m * 16 + fq * 4 + j) * 48 + n * 16 + fr] = acc[pp * 4 + m][n][j];
#pragma unroll
      for (int i = 0; i < 12; ++i) {
        const int item = i * 64 + lane;           // 64 rows x 12 chunks(4 f32)
        const int row = item / 12, ck = item % 12;
        f32x4 v = *(const f32x4*)&epi[row * 48 + ck * 4];
        const int grow = bm * 256 + wr * 128 + pp * 64 + row;
        const int gcol = bn * 192 + wc * 48 + ck * 4;
        *(f32x4*)&C[(size_t)grow * N + gcol] = v;
      }
    }
  }
}

// ---------------- K2: dwconv(k=3) + product, vectorized, transpose+reverse ----------------
__global__ __launch_bounds__(256) void dwconv_mul(
    const f16* __restrict__ kv,
    const float* __restrict__ sck_w, const float* __restrict__ sck_b,
    const float* __restrict__ scv_w, const float* __restrict__ scv_b,
    f16* __restrict__ ur) {
  __shared__ float ks[66][72];
  __shared__ float vs[66][72];
  const int b  = blockIdx.z;
  const int d0 = blockIdx.y * 64;
  const int t0 = blockIdx.x * 64;
  const int i  = threadIdx.x;
  const f16* base = kv + (size_t)b * kL * (2 * kD);
  for (int r = i >> 3; r < 66; r += 32) {
    const int c = (i & 7) * 8;
    const int t = t0 - 1 + r;
    float4 ka = {0,0,0,0}, kb4 = {0,0,0,0}, va = {0,0,0,0}, vb = {0,0,0,0};
    if (t >= 0 && t < kL) {
      f16x8 kk = *(const f16x8*)&base[(size_t)t * (2 * kD) + d0 + c];
      f16x8 vv = *(const f16x8*)&base[(size_t)t * (2 * kD) + kD + d0 + c];
      ka = make_float4((float)kk[0], (float)kk[1], (float)kk[2], (float)kk[3]);
      kb4 = make_float4((float)kk[4], (float)kk[5], (float)kk[6], (float)kk[7]);
      va = make_float4((float)vv[0], (float)vv[1], (float)vv[2], (float)vv[3]);
      vb = make_float4((float)vv[4], (float)vv[5], (float)vv[6], (float)vv[7]);
    }
    *(float4*)&ks[r][c] = ka; *(float4*)&ks[r][c + 4] = kb4;
    *(float4*)&vs[r][c] = va; *(float4*)&vs[r][c + 4] = vb;
  }
  __syncthreads();
  const int dd = i & 63;
  const int d  = d0 + dd;
  const float kw0 = sck_w[d * 3 + 0], kw1 = sck_w[d * 3 + 1], kw2 = sck_w[d * 3 + 2];
  const float vw0 = scv_w[d * 3 + 0], vw1 = scv_w[d * 3 + 1], vw2 = scv_w[d * 3 + 2];
  const float kbi = sck_b[d], vbi = scv_b[d];
  f16* urow = ur + ((size_t)b * kD + d) * UR;
#pragma unroll
  for (int rep = 0; rep < 2; ++rep) {
    const int to = (i >> 6) + 4 * rep;
    const int R  = to * 8;
    float k0 = ks[R][dd],     k1 = ks[R + 1][dd];
    float v0 = vs[R][dd],     v1 = vs[R + 1][dd];
    f16x8 outv;
#pragma unroll
    for (int e = 0; e < 8; ++e) {
      float k2 = ks[R + 2 + e][dd];
      float v2 = vs[R + 2 + e][dd];
      float kc = kw0 * k0 + kw1 * k1 + kw2 * k2 + kbi;
      float vc = vw0 * v0 + vw1 * v1 + vw2 * v2 + vbi;
      outv[7 - e] = (f16)(kc * vc);
      k0 = k1; k1 = k2; v0 = v1; v1 = v2;
    }
    *(f16x8*)&urow[kL - t0 - to * 8 - 8] = outv;
  }
  if (t0 == 0 && i < 64) {
    float kc = kw1 * ks[0][dd] + kw2 * ks[1][dd] + kbi;
    float vc = vw1 * vs[0][dd] + vw2 * vs[1][dd] + vbi;
    urow[kL] = (f16)(kc * vc);
  }
}

// ---------------- K3: hyena filter (t-parallel) -> hp16[d][32 + t]; pads zeroed ----------------
__global__ __launch_bounds__(256) void hyena_filter(
    const float* __restrict__ w1, const float* __restrict__ b1,
    const float* __restrict__ w2, const float* __restrict__ b2,
    const float* __restrict__ w3, const float* __restrict__ b3,
    const float* __restrict__ log_decay, f16* __restrict__ hp16) {
  __shared__ float w1s[64 * 65];
  __shared__ float w2s[64 * 65];
  __shared__ float pe[32][65];
  __shared__ float h1s[32][65];
  __shared__ float h2s[32][64];
  const int tid = threadIdx.x;
  if (blockIdx.x == 0) {
    for (int d = tid; d < kD; d += 256) {
      f16* row = hp16 + (size_t)d * HR;
      *(f16x8*)&row[0]  = (f16x8){}; *(f16x8*)&row[8]  = (f16x8){};
      *(f16x8*)&row[16] = (f16x8){}; *(f16x8*)&row[24] = (f16x8){};
      *(f16x8*)&row[8224] = (f16x8){}; *(f16x8*)&row[8232] = (f16x8){};
    }
  }
  for (int i = tid; i < 64 * 64; i += 256) {
    w1s[(i >> 6) * 65 + (i & 63)] = w1[i];
    w2s[(i >> 6) * 65 + (i & 63)] = w2[i];
  }
  const int tbase = blockIdx.x * 32;
  const int tt = tid >> 3;
  const int oc = (tid & 7) * 8;
  const float TWO_PI = 6.28318530717958647692f;
  {
    float tn = (float)(tbase + tt) / 8191.0f;
#pragma unroll
    for (int e = 0; e < 8; ++e) {
      int j = oc + e;
      float f = TWO_PI * (float)((j & 31) + 1);
      pe[tt][j] = (j < 32) ? sinf(tn * f) : cosf(tn * f);
    }
  }
  __syncthreads();
  {
    float s[8];
#pragma unroll
    for (int e = 0; e < 8; ++e) s[e] = b1[oc + e];
    for (int j = 0; j < 64; ++j) {
      float p = pe[tt][j];
#pragma unroll
      for (int e = 0; e < 8; ++e) s[e] += p * w1s[(oc + e) * 65 + j];
    }
#pragma unroll
    for (int e = 0; e < 8; ++e) h1s[tt][oc + e] = s[e] / (1.0f + expf(-s[e]));
  }
  __syncthreads();
  {
    float s[8];
#pragma unroll
    for (int e = 0; e < 8; ++e) s[e] = b2[oc + e];
    for (int j = 0; j < 64; ++j) {
      float p = h1s[tt][j];
#pragma unroll
      for (int e = 0; e < 8; ++e) s[e] += p * w2s[(oc + e) * 65 + j];
    }
#pragma unroll
    for (int e = 0; e < 8; ++e) h2s[tt][oc + e] = s[e] / (1.0f + expf(-s[e]));
  }
  __syncthreads();
  for (int d = tid; d < kD; d += 256) {
    float a = fabsf(log_decay[d]);
    float bb = b3[d];
    float acc[32];
#pragma unroll
    for (int t2 = 0; t2 < 32; ++t2) acc[t2] = bb;
    for (int j = 0; j < 64; ++j) {
      float w = w3[d * 64 + j];
#pragma unroll
      for (int t2 = 0; t2 < 32; ++t2) acc[t2] += h2s[t2][j] * w;
    }
    for (int t2 = 0; t2 < 32; ++t2) {
      int t = tbase + t2;
      hp16[(size_t)d * HR + 32 + t] = (f16)(acc[t2] * expf(-a * (float)t));
    }
  }
}

// ---------------- truncation length ----------------
__device__ __forceinline__ int trunc_len(float a) {
  int Td = (a * (float)kL <= 16.0f) ? kL : ((int)(16.0f / a) + 1);
  Td = (Td + 7) & ~7;
  return min(Td, kL);
}

// ---------------- K4: long conv via MFMA Toeplitz, 4-wave s-split + prefetch ----------------
__device__ __forceinline__ void bmask(f16x8& v, int X) {
  if (X < 0 || X > kL) { v = (f16x8){}; return; }
  uint32_t* u = (uint32_t*)&v;
  if (X == 0)  { u[0] &= 0xFFFFu; u[1] = 0; u[2] = 0; u[3] = 0; }
  else if (X == kL) { u[0] &= 0xFFFF0000u; }
}
__global__ __launch_bounds__(256) void long_conv_mfma(
    const f16* __restrict__ ur, const f16* __restrict__ hp,
    const float* __restrict__ log_decay, f16* __restrict__ y16) {
  __shared__ float red[3][8][72];
  const int wid  = threadIdx.x >> 6;   // 0..3
  const int lane = threadIdx.x & 63;
  const int gb = blockIdx.x;           // 0..24575
  const int d  = gb >> 5;
  const int tc = gb & 31;
  const int T0 = tc << 8;
  const int fr = lane & 15, fq = lane >> 4;
  const float a = fabsf(log_decay[d]);
  const int S = min(trunc_len(a), T0 + 256);
  const int nck = (((S + 31) & ~31) >> 5) + 1;
  const f16* hrow = hp + (size_t)d * HR;
  const f16* u0 = ur + (size_t)d * UR;
  const f16* u1 = ur + (size_t)(kD + d) * UR;
  const int abase = 8 * fq + fr;
  const int xbase = T0 + 16 * fr - 8 * fq + 32;
  f32x4 acc0 = {0.f, 0.f, 0.f, 0.f};
  f32x4 acc1 = {0.f, 0.f, 0.f, 0.f};

  int c = wid;
  if (c < nck) {
    int s0 = c << 5;
    f16x8 af;
    {
      const f16* hb = hrow + s0 + abase;
#pragma unroll
      for (int e = 0; e < 8; ++e) af[e] = hb[e];
    }
    int X = xbase - s0;
    f16x8 b0 = *(const f16x8*)(u0 + (kL - X));
    f16x8 b1 = *(const f16x8*)(u1 + (kL - X));
    for (;;) {
      const int cn = c + 4;
      const bool more = cn < nck;
      f16x8 naf, nb0, nb1;
      int nX = 0;
      if (more) {
        const int s0n = cn << 5;
        const f16* hb = hrow + s0n + abase;
#pragma unroll
        for (int e = 0; e < 8; ++e) naf[e] = hb[e];
        nX = xbase - s0n;
        nb0 = *(const f16x8*)(u0 + (kL - nX));
        nb1 = *(const f16x8*)(u1 + (kL - nX));
      }
      bmask(b0, X);
      bmask(b1, X);
      acc0 = __builtin_amdgcn_mfma_f32_16x16x32_f16(af, b0, acc0, 0, 0, 0);
      acc1 = __builtin_amdgcn_mfma_f32_16x16x32_f16(af, b1, acc1, 0, 0, 0);
      if (!more) break;
      af = naf; b0 = nb0; b1 = nb1; X = nX; c = cn;
    }
  }

  if (wid != 0) {
#pragma unroll
    for (int j = 0; j < 4; ++j) {
      red[wid - 1][j][lane]     = acc0[j];
      red[wid - 1][4 + j][lane] = acc1[j];
    }
  }
  __syncthreads();
  if (wid == 0) {
#pragma unroll
    for (int w = 0; w < 3; ++w)
#pragma unroll
      for (int j = 0; j < 4; ++j) {
        acc0[j] += red[w][j][lane];
        acc1[j] += red[w][4 + j][lane];
      }
    const size_t off = (size_t)T0 + 16 * fr + 4 * fq;
    f16x4 o0, o1;
#pragma unroll
    for (int j = 0; j < 4; ++j) { o0[j] = (f16)acc0[j]; o1[j] = (f16)acc1[j]; }
    *(f16x4*)&y16[(size_t)d * kL + off] = o0;
    *(f16x4*)&y16[(size_t)(kD + d) * kL + off] = o1;
  }
}

// ---------------- K5: gate + transpose (vectorized) ----------------
__global__ __launch_bounds__(256) void gate_transpose(
    const f16* __restrict__ q, const f16* __restrict__ y16,
    f16* __restrict__ g) {
  __shared__ f16 ys[64][72];
  const int b  = blockIdx.z;
  const int t0 = blockIdx.x * 64;
  const int d0 = blockIdx.y * 64;
  const int i  = threadIdx.x;
#pragma unroll
  for (int rep = 0; rep < 2; ++rep) {
    const int dd = (i >> 3) + rep * 32;
    const int tc = i & 7;
    f16x8 v = *(const f16x8*)&y16[((size_t)b * kD + d0 + dd) * kL + t0 + tc * 8];
    *(f16x8*)&ys[dd][tc * 8] = v;
  }
  __syncthreads();
  const f16* qb = q + (size_t)b * kL * kD;
  f16* gb = g + (size_t)b * kL * kD;
#pragma unroll
  for (int rep = 0; rep < 2; ++rep) {
    const int tt = (i >> 3) + rep * 32;
    const int dc = i & 7;
    const size_t row = (size_t)(t0 + tt) * kD + d0 + dc * 8;
    f16x8 qv = *(const f16x8*)&qb[row];
    f16x8 ov;
#pragma unroll
    for (int e = 0; e < 8; ++e) {
      float qf = (float)qv[e];
      float sq = qf / (1.0f + expf(-qf));
      ov[e] = (f16)(sq * (float)ys[dc * 8 + e][tt]);
    }
    *(f16x8*)&gb[row] = ov;
  }
}

}  // namespace

extern "C" void kernel_launch(void* const* d_in, const int* in_sizes, int n_in,
                              void* d_out, int out_size, void* d_ws, size_t ws_size,
                              hipStream_t stream) {
  const float* x          = (const float*)d_in[0];
  const float* in_proj_w  = (const float*)d_in[1];
  const float* sck_w      = (const float*)d_in[2];
  const float* sck_b      = (const float*)d_in[3];
  const float* scv_w      = (const float*)d_in[4];
  const float* scv_b      = (const float*)d_in[5];
  const float* mlp_w1     = (const float*)d_in[6];
  const float* mlp_b1     = (const float*)d_in[7];
  const float* mlp_w2     = (const float*)d_in[8];
  const float* mlp_b2     = (const float*)d_in[9];
  const float* mlp_w3     = (const float*)d_in[10];
  const float* mlp_b3     = (const float*)d_in[11];
  const float* log_decay  = (const float*)d_in[12];
  const float* out_proj_w = (const float*)d_in[13];
  float* out = (float*)d_out;

  // workspace layout (bytes), ~143 MB total
  char* base = (char*)d_ws;
  const size_t S1  = 25165824;                      // q16  [B][L][D] fp16
  const size_t S2  = 50331648;                      // kv16 -> later y16 [B][D][L] f16
  const size_t Sur = (size_t)kB * kD * UR * 2;      // ur   reversed u
  const size_t S4  = 25165824;                      // x16 -> later g16
  const size_t Shp = (size_t)kD * HR * 2;           // hp16 padded filter
  f16*   q16   = (f16*)base;
  f16*   kv16  = (f16*)(base + S1);
  f16*   y16   = (f16*)(base + S1);                 // overlays kv16 after K2
  f16*   ur    = (f16*)(base + S1 + S2);
  f16*   x16   = (f16*)(base + S1 + S2 + Sur);
  f16*   g16   = x16;
  f16*   hp16  = (f16*)(base + S1 + S2 + Sur + S4);
  f16*   w16in = (f16*)(base + S1 + S2 + Sur + S4 + Shp);
  f16*   w16out= w16in + (size_t)3 * kD * kD;

  // K0: fused fp32 -> fp16 conversions (x, in_proj_w, out_proj_w)
  {
    const int n1 = kB * kL * kD;
    const int n2 = 3 * kD * kD;
    const int n3 = kD * kD;
    const int total8 = (n1 + n2 + n3) / 8;
    cvt3<<<(total8 + 255) / 256, 256, 0, stream>>>(
        x, x16, n1, in_proj_w, w16in, n2, out_proj_w, w16out, n3);
  }

  // K1: {q16, kv16} = x16 @ w16in^T  (M=16384, N=2304, K=768; 768 blocks = 3 rounds)
  hgemm256<0><<<dim3(12, 64), 512, 0, stream>>>(
      x16, w16in, q16, kv16, nullptr, 0);

  // K2: ur[b,d,kL-t] = conv_k * conv_v  (vectorized 64x64 tiles)
  dwconv_mul<<<dim3(kL / 64, kD / 64, kB), 256, 0, stream>>>(
      kv16, sck_w, sck_b, scv_w, scv_b, ur);

  // K3: filter hp16[d][32+t]  (t-parallel; zeroes its own pads)
  hyena_filter<<<dim3(kL / 32), 256, 0, stream>>>(
      mlp_w1, mlp_b1, mlp_w2, mlp_b2, mlp_w3, mlp_b3, log_decay, hp16);

  // K4: y16 = causal conv via MFMA Toeplitz; block per (d, t-tile), 4-wave s-split
  long_conv_mfma<<<kD * 32, 256, 0, stream>>>(ur, hp16, log_decay, y16);

  // K5: g16[b,t,d] = silu(q16) * y16  (vectorized 64x64 tiles)
  gate_transpose<<<dim3(kL / 64, kD / 64, kB), 256, 0, stream>>>(q16, y16, g16);

  // K6: out = g16 @ w16out^T  (M=16384, N=768, K=768; 256 blocks = 1 round)
  hgemm256<1><<<dim3(4, 64), 512, 0, stream>>>(
      g16, w16out, nullptr, nullptr, out, kD);
}

// Round 21
// 229.005 us; speedup vs baseline: 1.0983x; 1.0343x over previous
//
#include <hip/hip_runtime.h>
#include <math.h>

namespace {

constexpr int kB  = 2;
constexpr int kL  = 8192;
constexpr int kD  = 768;
constexpr int HR  = 8240;  // hp16 row stride (f16): [32 zeros][8192 h][16 zero pad]
constexpr int UR  = 8200;  // ur row stride (f16): ur[8192 - t] = u[t]

typedef _Float16 f16;
typedef __attribute__((ext_vector_type(4))) _Float16 f16x4;
typedef __attribute__((ext_vector_type(8))) _Float16 f16x8;
typedef __attribute__((ext_vector_type(4))) float f32x4;

__device__ __forceinline__ void gload_lds16(const f16* g, f16* l) {
  __builtin_amdgcn_global_load_lds(
      (__attribute__((address_space(1))) void*)(g),
      (__attribute__((address_space(3))) void*)(l), 16, 0, 0);
}

__device__ __forceinline__ void cvt8(const float* s, f16* d, int i) {
  float4 a = *(const float4*)(s + i);
  float4 b = *(const float4*)(s + i + 4);
  f16x8 v;
  v[0] = (f16)a.x; v[1] = (f16)a.y; v[2] = (f16)a.z; v[3] = (f16)a.w;
  v[4] = (f16)b.x; v[5] = (f16)b.y; v[6] = (f16)b.z; v[7] = (f16)b.w;
  *(f16x8*)(d + i) = v;
}

// ---------------- K0: fused fp32 -> fp16 conversions (4 buffers) ----------------
__global__ __launch_bounds__(256) void cvt4(
    const float* __restrict__ s1, f16* __restrict__ d1, int n1,
    const float* __restrict__ s2, f16* __restrict__ d2, int n2,
    const float* __restrict__ s3, f16* __restrict__ d3, int n3,
    const float* __restrict__ s4, f16* __restrict__ d4, int n4) {
  int i = (blockIdx.x * 256 + threadIdx.x) * 8;
  if (i < n1) { cvt8(s1, d1, i); return; }
  i -= n1;
  if (i < n2) { cvt8(s2, d2, i); return; }
  i -= n2;
  if (i < n3) { cvt8(s3, d3, i); return; }
  i -= n3;
  if (i < n4) cvt8(s4, d4, i);
}

// ============ K1/K6: 256x192 tile, BK=64, mh-major phases, counted vmcnt ====
template <int MODE>
__global__ __launch_bounds__(512, 2) void hgemm256(
    const f16* __restrict__ A, const f16* __restrict__ W,
    f16* __restrict__ q16, f16* __restrict__ kv16,
    float* __restrict__ C, int N) {
  constexpr int K  = 768;
  constexpr int NT = K / 64;          // 12 K-tiles
  constexpr int BUFA = 256 * 64;
  constexpr int BUFB = 192 * 64;
  __shared__ f16 As[2 * BUFA];
  __shared__ f16 Bs[2 * BUFB];
  const int tid  = threadIdx.x;
  const int wid  = tid >> 6;
  const int lane = tid & 63;
  const int nwg = gridDim.x * gridDim.y;
  const int lin = blockIdx.y * gridDim.x + blockIdx.x;
  const int wg  = (lin & 7) * (nwg >> 3) + (lin >> 3);
  const int bm = wg / gridDim.x;
  const int bn = wg % gridDim.x;
  const int wr = wid >> 2, wc = wid & 3;
  const int fr = lane & 15, fq = lane >> 4;
  const int srow = tid >> 3;
  const int scg  = ((tid & 7) ^ (srow & 7)) * 8;
  const int rsw  = fr & 7;
  const f16* Ab = A + (size_t)bm * 256 * K;
  const f16* Wb = W + (size_t)bn * 192 * K;
  const int dstoff = wid * 512;

  f32x4 acc[8][3];
#pragma unroll
  for (int m = 0; m < 8; ++m)
#pragma unroll
    for (int n = 0; n < 3; ++n)
#pragma unroll
      for (int j = 0; j < 4; ++j) acc[m][n][j] = 0.f;

  auto STG_A1 = [&](int buf, int t, int i) {
    gload_lds16(Ab + (size_t)(i * 64 + srow) * K + t * 64 + scg,
                As + buf * BUFA + i * 4096 + dstoff);
  };
  auto STG_B1 = [&](int buf, int t, int i) {
    gload_lds16(Wb + (size_t)(i * 64 + srow) * K + t * 64 + scg,
                Bs + buf * BUFB + i * 4096 + dstoff);
  };

  // prologue ledger: A02(0) B01(0) B2(0)A1(0) A3(0) A02(1)
  STG_A1(0, 0, 0); STG_A1(0, 0, 2);
  STG_B1(0, 0, 0); STG_B1(0, 0, 1);
  STG_B1(0, 0, 2); STG_A1(0, 0, 1);
  STG_A1(0, 0, 3);
  STG_A1(1, 1, 0); STG_A1(1, 1, 2);

  for (int t = 0; t < NT; ++t) {
    const int p = t & 1;
    const f16* Ac = As + p * BUFA;
    const f16* Bc = Bs + p * BUFB;
    const bool hasN1 = (t + 1 < NT);
    const bool hasN2 = (t + 2 < NT);

    if (hasN1) asm volatile("s_waitcnt vmcnt(2)" ::: "memory");
    else       asm volatile("s_waitcnt vmcnt(0)" ::: "memory");
    __builtin_amdgcn_sched_barrier(0);
    __builtin_amdgcn_s_barrier();
    __builtin_amdgcn_sched_barrier(0);

    const int ch0 = (fq ^ rsw) << 3;
    const int ch1 = ((4 + fq) ^ rsw) << 3;
    f16x8 bf0[3], bf1[3], af[4];

    // ---- P1: mh0, kk0 ----
#pragma unroll
    for (int n = 0; n < 3; ++n)
      bf0[n] = *(const f16x8*)&Bc[(wc * 48 + n * 16 + fr) * 64 + ch0];
#pragma unroll
    for (int m = 0; m < 4; ++m)
      af[m] = *(const f16x8*)&Ac[(wr * 128 + m * 16 + fr) * 64 + ch0];
    if (hasN1) { STG_B1(p ^ 1, t + 1, 0); STG_B1(p ^ 1, t + 1, 1); }
    asm volatile("s_waitcnt lgkmcnt(0)" ::: "memory");
    __builtin_amdgcn_sched_barrier(0);
    __builtin_amdgcn_s_setprio(1);
#pragma unroll
    for (int m = 0; m < 4; ++m)
#pragma unroll
      for (int n = 0; n < 3; ++n)
        acc[m][n] = __builtin_amdgcn_mfma_f32_16x16x32_f16(af[m], bf0[n], acc[m][n], 0, 0, 0);
    __builtin_amdgcn_s_setprio(0);

    // ---- P2: mh0, kk1 ----
#pragma unroll
    for (int n = 0; n < 3; ++n)
      bf1[n] = *(const f16x8*)&Bc[(wc * 48 + n * 16 + fr) * 64 + ch1];
#pragma unroll
    for (int m = 0; m < 4; ++m)
      af[m] = *(const f16x8*)&Ac[(wr * 128 + m * 16 + fr) * 64 + ch1];
    if (hasN1) { STG_B1(p ^ 1, t + 1, 2); STG_A1(p ^ 1, t + 1, 1); }
    asm volatile("s_waitcnt lgkmcnt(0)" ::: "memory");
    __builtin_amdgcn_sched_barrier(0);
    __builtin_amdgcn_s_setprio(1);
#pragma unroll
    for (int m = 0; m < 4; ++m)
#pragma unroll
      for (int n = 0; n < 3; ++n)
        acc[m][n] = __builtin_amdgcn_mfma_f32_16x16x32_f16(af[m], bf1[n], acc[m][n], 0, 0, 0);
    __builtin_amdgcn_s_setprio(0);

    __builtin_amdgcn_sched_barrier(0);
    __builtin_amdgcn_s_barrier();
    __builtin_amdgcn_sched_barrier(0);

    // ---- P3: mh1, kk0 (bf0 reused) ----
#pragma unroll
    for (int m = 0; m < 4; ++m)
      af[m] = *(const f16x8*)&Ac[(wr * 128 + 64 + m * 16 + fr) * 64 + ch0];
    if (hasN1) STG_A1(p ^ 1, t + 1, 3);
    asm volatile("s_waitcnt lgkmcnt(0)" ::: "memory");
    __builtin_amdgcn_sched_barrier(0);
    __builtin_amdgcn_s_setprio(1);
#pragma unroll
    for (int m = 0; m < 4; ++m)
#pragma unroll
      for (int n = 0; n < 3; ++n)
        acc[4 + m][n] = __builtin_amdgcn_mfma_f32_16x16x32_f16(af[m], bf0[n], acc[4 + m][n], 0, 0, 0);
    __builtin_amdgcn_s_setprio(0);

    // ---- P4: mh1, kk1 (bf1 reused) ----
#pragma unroll
    for (int m = 0; m < 4; ++m)
      af[m] = *(const f16x8*)&Ac[(wr * 128 + 64 + m * 16 + fr) * 64 + ch1];
    if (hasN2) { STG_A1(p, t + 2, 0); STG_A1(p, t + 2, 2); }
    asm volatile("s_waitcnt lgkmcnt(0)" ::: "memory");
    __builtin_amdgcn_sched_barrier(0);
    __builtin_amdgcn_s_setprio(1);
#pragma unroll
    for (int m = 0; m < 4; ++m)
#pragma unroll
      for (int n = 0; n < 3; ++n)
        acc[4 + m][n] = __builtin_amdgcn_mfma_f32_16x16x32_f16(af[m], bf1[n], acc[4 + m][n], 0, 0, 0);
    __builtin_amdgcn_s_setprio(0);
  }

  // ---- epilogue: LDS-transposed, vectorized coalesced stores ----
  __builtin_amdgcn_s_barrier();
  if constexpr (MODE == 0) {
    f16* epi = As + wid * (64 * 56);
#pragma unroll
    for (int pp = 0; pp < 2; ++pp) {
#pragma unroll
      for (int m = 0; m < 4; ++m)
#pragma unroll
        for (int n = 0; n < 3; ++n)
#pragma unroll
          for (int j = 0; j < 4; ++j)
            epi[(m * 16 + fq * 4 + j) * 56 + n * 16 + fr] = (f16)acc[pp * 4 + m][n][j];
#pragma unroll
      for (int i = 0; i < 6; ++i) {
        const int item = i * 64 + lane;
        const int row = item / 6, ck = item % 6;
        f16x8 v = *(const f16x8*)&epi[row * 56 + ck * 8];
        const int grow = bm * 256 + wr * 128 + pp * 64 + row;
        const int gcol = bn * 192 + wc * 48 + ck * 8;
        f16* dst;
        int ldc, col;
        if (gcol < 768) { dst = q16; ldc = 768; col = gcol; }
        else            { dst = kv16; ldc = 1536; col = gcol - 768; }
        *(f16x8*)&dst[(size_t)grow * ldc + col] = v;
      }
    }
  } else {
    float* epi = (wid < 4) ? ((float*)As + wid * (64 * 48))
                           : ((float*)Bs + (wid - 4) * (64 * 48));
#pragma unroll
    for (int pp = 0; pp < 2; ++pp) {
#pragma unroll
      for (int m = 0; m < 4; ++m)
#pragma unroll
        for (int n = 0; n < 3; ++n)
#pragma unroll
          for (int j = 0; j < 4; ++j)
            epi[(m * 16 + fq * 4 + j) * 48 + n * 16 + fr] = acc[pp * 4 + m][n][j];
#pragma unroll
      for (int i = 0; i < 12; ++i) {
        const int item = i * 64 + lane;
        const int row = item / 12, ck = item % 12;
        f32x4 v = *(const f32x4*)&epi[row * 48 + ck * 4];
        const int grow = bm * 256 + wr * 128 + pp * 64 + row;
        const int gcol = bn * 192 + wc * 48 + ck * 4;
        *(f32x4*)&C[(size_t)grow * N + gcol] = v;
      }
    }
  }
}

// ---------------- K2: dwconv(k=3) + product, vectorized, transpose+reverse ----------------
__global__ __launch_bounds__(256) void dwconv_mul(
    const f16* __restrict__ kv,
    const float* __restrict__ sck_w, const float* __restrict__ sck_b,
    const float* __restrict__ scv_w, const float* __restrict__ scv_b,
    f16* __restrict__ ur) {
  __shared__ float ks[66][72];
  __shared__ float vs[66][72];
  const int b  = blockIdx.z;
  const int d0 = blockIdx.y * 64;
  const int t0 = blockIdx.x * 64;
  const int i  = threadIdx.x;
  const f16* base = kv + (size_t)b * kL * (2 * kD);
  for (int r = i >> 3; r < 66; r += 32) {
    const int c = (i & 7) * 8;
    const int t = t0 - 1 + r;
    float4 ka = {0,0,0,0}, kb4 = {0,0,0,0}, va = {0,0,0,0}, vb = {0,0,0,0};
    if (t >= 0 && t < kL) {
      f16x8 kk = *(const f16x8*)&base[(size_t)t * (2 * kD) + d0 + c];
      f16x8 vv = *(const f16x8*)&base[(size_t)t * (2 * kD) + kD + d0 + c];
      ka = make_float4((float)kk[0], (float)kk[1], (float)kk[2], (float)kk[3]);
      kb4 = make_float4((float)kk[4], (float)kk[5], (float)kk[6], (float)kk[7]);
      va = make_float4((float)vv[0], (float)vv[1], (float)vv[2], (float)vv[3]);
      vb = make_float4((float)vv[4], (float)vv[5], (float)vv[6], (float)vv[7]);
    }
    *(float4*)&ks[r][c] = ka; *(float4*)&ks[r][c + 4] = kb4;
    *(float4*)&vs[r][c] = va; *(float4*)&vs[r][c + 4] = vb;
  }
  __syncthreads();
  const int dd = i & 63;
  const int d  = d0 + dd;
  const float kw0 = sck_w[d * 3 + 0], kw1 = sck_w[d * 3 + 1], kw2 = sck_w[d * 3 + 2];
  const float vw0 = scv_w[d * 3 + 0], vw1 = scv_w[d * 3 + 1], vw2 = scv_w[d * 3 + 2];
  const float kbi = sck_b[d], vbi = scv_b[d];
  f16* urow = ur + ((size_t)b * kD + d) * UR;
#pragma unroll
  for (int rep = 0; rep < 2; ++rep) {
    const int to = (i >> 6) + 4 * rep;
    const int R  = to * 8;
    float k0 = ks[R][dd],     k1 = ks[R + 1][dd];
    float v0 = vs[R][dd],     v1 = vs[R + 1][dd];
    f16x8 outv;
#pragma unroll
    for (int e = 0; e < 8; ++e) {
      float k2 = ks[R + 2 + e][dd];
      float v2 = vs[R + 2 + e][dd];
      float kc = kw0 * k0 + kw1 * k1 + kw2 * k2 + kbi;
      float vc = vw0 * v0 + vw1 * v1 + vw2 * v2 + vbi;
      outv[7 - e] = (f16)(kc * vc);
      k0 = k1; k1 = k2; v0 = v1; v1 = v2;
    }
    *(f16x8*)&urow[kL - t0 - to * 8 - 8] = outv;
  }
  if (t0 == 0 && i < 64) {
    float kc = kw1 * ks[0][dd] + kw2 * ks[1][dd] + kbi;
    float vc = vw1 * vs[0][dd] + vw2 * vs[1][dd] + vbi;
    urow[kL] = (f16)(kc * vc);
  }
}

// ---------------- K3a: hyena MLP -> h2f[8192][64] (f16); zeroes hp16 pads ----------------
__global__ __launch_bounds__(256) void hyena_mlp(
    const float* __restrict__ w1, const float* __restrict__ b1,
    const float* __restrict__ w2, const float* __restrict__ b2,
    f16* __restrict__ h2f, f16* __restrict__ hp16) {
  __shared__ float w1s[64 * 65];
  __shared__ float w2s[64 * 65];
  __shared__ float pe[32][65];
  __shared__ float h1s[32][65];
  const int tid = threadIdx.x;
  if (blockIdx.x == 0) {
    for (int d = tid; d < kD; d += 256) {
      f16* row = hp16 + (size_t)d * HR;
      *(f16x8*)&row[0]  = (f16x8){}; *(f16x8*)&row[8]  = (f16x8){};
      *(f16x8*)&row[16] = (f16x8){}; *(f16x8*)&row[24] = (f16x8){};
      *(f16x8*)&row[8224] = (f16x8){}; *(f16x8*)&row[8232] = (f16x8){};
    }
  }
  for (int i = tid; i < 64 * 64; i += 256) {
    w1s[(i >> 6) * 65 + (i & 63)] = w1[i];
    w2s[(i >> 6) * 65 + (i & 63)] = w2[i];
  }
  const int tbase = blockIdx.x * 32;
  const int tt = tid >> 3;
  const int oc = (tid & 7) * 8;
  const float TWO_PI = 6.28318530717958647692f;
  {
    float tn = (float)(tbase + tt) / 8191.0f;
#pragma unroll
    for (int e = 0; e < 8; ++e) {
      int j = oc + e;
      float f = TWO_PI * (float)((j & 31) + 1);
      pe[tt][j] = (j < 32) ? sinf(tn * f) : cosf(tn * f);
    }
  }
  __syncthreads();
  {
    float s[8];
#pragma unroll
    for (int e = 0; e < 8; ++e) s[e] = b1[oc + e];
    for (int j = 0; j < 64; ++j) {
      float p = pe[tt][j];
#pragma unroll
      for (int e = 0; e < 8; ++e) s[e] += p * w1s[(oc + e) * 65 + j];
    }
#pragma unroll
    for (int e = 0; e < 8; ++e) h1s[tt][oc + e] = s[e] / (1.0f + expf(-s[e]));
  }
  __syncthreads();
  {
    float s[8];
#pragma unroll
    for (int e = 0; e < 8; ++e) s[e] = b2[oc + e];
    for (int j = 0; j < 64; ++j) {
      float p = h1s[tt][j];
#pragma unroll
      for (int e = 0; e < 8; ++e) s[e] += p * w2s[(oc + e) * 65 + j];
    }
    f16x8 hv;
#pragma unroll
    for (int e = 0; e < 8; ++e) {
      float h = s[e] / (1.0f + expf(-s[e]));
      hv[e] = (f16)h;
    }
    *(f16x8*)&h2f[(size_t)(tbase + tt) * 64 + oc] = hv;
  }
}

// ---------------- K3b: hp16[d][32+t] = (h2.w3 + b3) * exp(-a_d t), MFMA ----------------
// 1 wave/block; block = 16-t tile; loop 48 d-tiles. A=w3f (m=d), B=h2f (n=t).
__global__ __launch_bounds__(64) void hyena_decay(
    const f16* __restrict__ w3f, const f16* __restrict__ h2f,
    const float* __restrict__ b3, const float* __restrict__ log_decay,
    f16* __restrict__ hp16) {
  const int lane = threadIdx.x;
  const int fr = lane & 15, fq = lane >> 4;
  const int T0 = blockIdx.x * 16;
  const f16x8 bfa = *(const f16x8*)&h2f[(size_t)(T0 + fr) * 64 + fq * 8];
  const f16x8 bfb = *(const f16x8*)&h2f[(size_t)(T0 + fr) * 64 + 32 + fq * 8];
  const float tloc = (float)(T0 + fr);
  for (int dt = 0; dt < 48; ++dt) {
    const int D0 = dt * 16;
    f16x8 a0 = *(const f16x8*)&w3f[(size_t)(D0 + fr) * 64 + fq * 8];
    f16x8 a1 = *(const f16x8*)&w3f[(size_t)(D0 + fr) * 64 + 32 + fq * 8];
    f32x4 acc = {0.f, 0.f, 0.f, 0.f};
    acc = __builtin_amdgcn_mfma_f32_16x16x32_f16(a0, bfa, acc, 0, 0, 0);
    acc = __builtin_amdgcn_mfma_f32_16x16x32_f16(a1, bfb, acc, 0, 0, 0);
#pragma unroll
    for (int j = 0; j < 4; ++j) {
      const int d = D0 + fq * 4 + j;
      const float av = fabsf(log_decay[d]);
      const float val = (acc[j] + b3[d]) * expf(-av * tloc);
      hp16[(size_t)d * HR + 32 + T0 + fr] = (f16)val;
    }
  }
}

// ---------------- truncation length ----------------
__device__ __forceinline__ int trunc_len(float a) {
  int Td = (a * (float)kL <= 16.0f) ? kL : ((int)(16.0f / a) + 1);
  Td = (Td + 7) & ~7;
  return min(Td, kL);
}

// ---------------- K4: long conv via MFMA Toeplitz, 4-wave s-split + prefetch ----------------
__device__ __forceinline__ void bmask(f16x8& v, int X) {
  if (X < 0 || X > kL) { v = (f16x8){}; return; }
  uint32_t* u = (uint32_t*)&v;
  if (X == 0)  { u[0] &= 0xFFFFu; u[1] = 0; u[2] = 0; u[3] = 0; }
  else if (X == kL) { u[0] &= 0xFFFF0000u; }
}
__global__ __launch_bounds__(256) void long_conv_mfma(
    const f16* __restrict__ ur, const f16* __restrict__ hp,
    const float* __restrict__ log_decay, f16* __restrict__ y16) {
  __shared__ float red[3][8][72];
  const int wid  = threadIdx.x >> 6;
  const int lane = threadIdx.x & 63;
  const int gb = blockIdx.x;
  const int d  = gb >> 5;
  const int tc = gb & 31;
  const int T0 = tc << 8;
  const int fr = lane & 15, fq = lane >> 4;
  const float a = fabsf(log_decay[d]);
  const int S = min(trunc_len(a), T0 + 256);
  const int nck = (((S + 31) & ~31) >> 5) + 1;
  const f16* hrow = hp + (size_t)d * HR;
  const f16* u0 = ur + (size_t)d * UR;
  const f16* u1 = ur + (size_t)(kD + d) * UR;
  const int abase = 8 * fq + fr;
  const int xbase = T0 + 16 * fr - 8 * fq + 32;
  f32x4 acc0 = {0.f, 0.f, 0.f, 0.f};
  f32x4 acc1 = {0.f, 0.f, 0.f, 0.f};

  int c = wid;
  if (c < nck) {
    int s0 = c << 5;
    f16x8 af;
    {
      const f16* hb = hrow + s0 + abase;
#pragma unroll
      for (int e = 0; e < 8; ++e) af[e] = hb[e];
    }
    int X = xbase - s0;
    f16x8 b0 = *(const f16x8*)(u0 + (kL - X));
    f16x8 b1 = *(const f16x8*)(u1 + (kL - X));
    for (;;) {
      const int cn = c + 4;
      const bool more = cn < nck;
      f16x8 naf, nb0, nb1;
      int nX = 0;
      if (more) {
        const int s0n = cn << 5;
        const f16* hb = hrow + s0n + abase;
#pragma unroll
        for (int e = 0; e < 8; ++e) naf[e] = hb[e];
        nX = xbase - s0n;
        nb0 = *(const f16x8*)(u0 + (kL - nX));
        nb1 = *(const f16x8*)(u1 + (kL - nX));
      }
      bmask(b0, X);
      bmask(b1, X);
      acc0 = __builtin_amdgcn_mfma_f32_16x16x32_f16(af, b0, acc0, 0, 0, 0);
      acc1 = __builtin_amdgcn_mfma_f32_16x16x32_f16(af, b1, acc1, 0, 0, 0);
      if (!more) break;
      af = naf; b0 = nb0; b1 = nb1; X = nX; c = cn;
    }
  }

  if (wid != 0) {
#pragma unroll
    for (int j = 0; j < 4; ++j) {
      red[wid - 1][j][lane]     = acc0[j];
      red[wid - 1][4 + j][lane] = acc1[j];
    }
  }
  __syncthreads();
  if (wid == 0) {
#pragma unroll
    for (int w = 0; w < 3; ++w)
#pragma unroll
      for (int j = 0; j < 4; ++j) {
        acc0[j] += red[w][j][lane];
        acc1[j] += red[w][4 + j][lane];
      }
    const size_t off = (size_t)T0 + 16 * fr + 4 * fq;
    f16x4 o0, o1;
#pragma unroll
    for (int j = 0; j < 4; ++j) { o0[j] = (f16)acc0[j]; o1[j] = (f16)acc1[j]; }
    *(f16x4*)&y16[(size_t)d * kL + off] = o0;
    *(f16x4*)&y16[(size_t)(kD + d) * kL + off] = o1;
  }
}

// ---------------- K5: gate + transpose (vectorized) ----------------
__global__ __launch_bounds__(256) void gate_transpose(
    const f16* __restrict__ q, const f16* __restrict__ y16,
    f16* __restrict__ g) {
  __shared__ f16 ys[64][72];
  const int b  = blockIdx.z;
  const int t0 = blockIdx.x * 64;
  const int d0 = blockIdx.y * 64;
  const int i  = threadIdx.x;
#pragma unroll
  for (int rep = 0; rep < 2; ++rep) {
    const int dd = (i >> 3) + rep * 32;
    const int tc = i & 7;
    f16x8 v = *(const f16x8*)&y16[((size_t)b * kD + d0 + dd) * kL + t0 + tc * 8];
    *(f16x8*)&ys[dd][tc * 8] = v;
  }
  __syncthreads();
  const f16* qb = q + (size_t)b * kL * kD;
  f16* gb = g + (size_t)b * kL * kD;
#pragma unroll
  for (int rep = 0; rep < 2; ++rep) {
    const int tt = (i >> 3) + rep * 32;
    const int dc = i & 7;
    const size_t row = (size_t)(t0 + tt) * kD + d0 + dc * 8;
    f16x8 qv = *(const f16x8*)&qb[row];
    f16x8 ov;
#pragma unroll
    for (int e = 0; e < 8; ++e) {
      float qf = (float)qv[e];
      float sq = qf / (1.0f + expf(-qf));
      ov[e] = (f16)(sq * (float)ys[dc * 8 + e][tt]);
    }
    *(f16x8*)&gb[row] = ov;
  }
}

}  // namespace

extern "C" void kernel_launch(void* const* d_in, const int* in_sizes, int n_in,
                              void* d_out, int out_size, void* d_ws, size_t ws_size,
                              hipStream_t stream) {
  const float* x          = (const float*)d_in[0];
  const float* in_proj_w  = (const float*)d_in[1];
  const float* sck_w      = (const float*)d_in[2];
  const float* sck_b      = (const float*)d_in[3];
  const float* scv_w      = (const float*)d_in[4];
  const float* scv_b      = (const float*)d_in[5];
  const float* mlp_w1     = (const float*)d_in[6];
  const float* mlp_b1     = (const float*)d_in[7];
  const float* mlp_w2     = (const float*)d_in[8];
  const float* mlp_b2     = (const float*)d_in[9];
  const float* mlp_w3     = (const float*)d_in[10];
  const float* mlp_b3     = (const float*)d_in[11];
  const float* log_decay  = (const float*)d_in[12];
  const float* out_proj_w = (const float*)d_in[13];
  float* out = (float*)d_out;

  // workspace layout (bytes), ~144.4 MB total
  char* base = (char*)d_ws;
  const size_t S1  = 25165824;                      // q16  [B][L][D] fp16
  const size_t S2  = 50331648;                      // kv16 -> later y16 [B][D][L] f16
  const size_t Sur = (size_t)kB * kD * UR * 2;      // ur   reversed u
  const size_t S4  = 25165824;                      // x16 -> later g16
  const size_t Shp = (size_t)kD * HR * 2;           // hp16 padded filter
  f16*   q16   = (f16*)base;
  f16*   kv16  = (f16*)(base + S1);
  f16*   y16   = (f16*)(base + S1);                 // overlays kv16 after K2
  f16*   ur    = (f16*)(base + S1 + S2);
  f16*   x16   = (f16*)(base + S1 + S2 + Sur);
  f16*   g16   = x16;
  f16*   hp16  = (f16*)(base + S1 + S2 + Sur + S4);
  f16*   w16in = (f16*)(base + S1 + S2 + Sur + S4 + Shp);
  f16*   w16out= w16in + (size_t)3 * kD * kD;
  f16*   w3f   = w16out + (size_t)kD * kD;          // [768][64] f16
  f16*   h2f   = w3f + (size_t)kD * 64;             // [8192][64] f16

  // K0: fused fp32 -> fp16 conversions (x, in_proj_w, out_proj_w, mlp_w3)
  {
    const int n1 = kB * kL * kD;
    const int n2 = 3 * kD * kD;
    const int n3 = kD * kD;
    const int n4 = kD * 64;
    const int total8 = (n1 + n2 + n3 + n4) / 8;
    cvt4<<<(total8 + 255) / 256, 256, 0, stream>>>(
        x, x16, n1, in_proj_w, w16in, n2, out_proj_w, w16out, n3,
        mlp_w3, w3f, n4);
  }

  // K1: {q16, kv16} = x16 @ w16in^T  (768 blocks = 3 exact rounds)
  hgemm256<0><<<dim3(12, 64), 512, 0, stream>>>(
      x16, w16in, q16, kv16, nullptr, 0);

  // K2: ur[b,d,kL-t] = conv_k * conv_v
  dwconv_mul<<<dim3(kL / 64, kD / 64, kB), 256, 0, stream>>>(
      kv16, sck_w, sck_b, scv_w, scv_b, ur);

  // K3a: MLP -> h2f (f16); block 0 zeroes hp16 pads
  hyena_mlp<<<dim3(kL / 32), 256, 0, stream>>>(
      mlp_w1, mlp_b1, mlp_w2, mlp_b2, h2f, hp16);

  // K3b: hp16 = (h2f @ w3f^T + b3) * decay  (MFMA; 512 one-wave blocks)
  hyena_decay<<<dim3(kL / 16), 64, 0, stream>>>(
      w3f, h2f, mlp_b3, log_decay, hp16);

  // K4: y16 = causal conv via MFMA Toeplitz; block per (d, t-tile), 4-wave s-split
  long_conv_mfma<<<kD * 32, 256, 0, stream>>>(ur, hp16, log_decay, y16);

  // K5: g16[b,t,d] = silu(q16) * y16
  gate_transpose<<<dim3(kL / 64, kD / 64, kB), 256, 0, stream>>>(q16, y16, g16);

  // K6: out = g16 @ w16out^T  (256 blocks = 1 exact round)
  hgemm256<1><<<dim3(4, 64), 512, 0, stream>>>(
      g16, w16out, nullptr, nullptr, out, kD);
}